// Round 6
// baseline (504.298 us; speedup 1.0000x reference)
//
#include <hip/hip_runtime.h>
#include <math.h>

// Problem constants
#define NB 8
#define NCH 64
#define NH 256
#define NW 256
#define NP (NH * NW)        // 65536 pixels per image
#define NS 64               // segments 1..64
#define NNC 256             // node classes
#define CLAMP_V 10.0f
#define EPS_V 1e-5f

#define BLKS_PER_B 64
#define PIX_PER_BLK (NP / BLKS_PER_B)   // 1024

// ---------------- Kernel 1: per-block partial segment pooling ----------------
// grid (BLKS_PER_B, NB), block 256.
// LDS accum layout [C][S+1] (stride 65 -> bank = (c+s)%32, spread by seg).
__global__ __launch_bounds__(256) void pool_partial(
    const float* __restrict__ feat,   // [B,C,H,W]
    const float* __restrict__ emb,    // [C,H,W]
    const int*   __restrict__ seg,    // [B,H,W]
    float* __restrict__ part_num,     // [B, BLKS_PER_B, C, S]
    float* __restrict__ part_den)     // [B, BLKS_PER_B, C, S]
{
    __shared__ float snum[NCH][NS + 1];
    __shared__ float sden[NCH][NS + 1];
    __shared__ int   segc[PIX_PER_BLK];

    const int tid = threadIdx.x;
    const int blk = blockIdx.x;
    const int b   = blockIdx.y;

    // zero accumulators
    float* zn = &snum[0][0];
    float* zd = &sden[0][0];
    for (int i = tid; i < NCH * (NS + 1); i += 256) { zn[i] = 0.f; zd[i] = 0.f; }

    // cache this block's segment ids (int4-coalesced)
    const int p_base = blk * PIX_PER_BLK;
    const int4* gseg = reinterpret_cast<const int4*>(seg + (size_t)b * NP + p_base);
    reinterpret_cast<int4*>(segc)[tid] = gseg[tid];
    __syncthreads();

    // each thread owns 4 consecutive pixels for every channel
    const int s0 = segc[tid * 4 + 0];
    const int s1 = segc[tid * 4 + 1];
    const int s2 = segc[tid * 4 + 2];
    const int s3 = segc[tid * 4 + 3];

    const float4* fbase = reinterpret_cast<const float4*>(feat)
                        + (size_t)b * (NCH * (NP / 4)) + (p_base / 4) + tid;
    const float4* ebase = reinterpret_cast<const float4*>(emb)
                        + (p_base / 4) + tid;

    #pragma unroll 2
    for (int c = 0; c < NCH; ++c) {
        const float4 fv = fbase[c * (NP / 4)];
        const float4 ev = ebase[c * (NP / 4)];

        float f, e;
        f = fminf(fmaxf(fv.x + ev.x, -CLAMP_V), CLAMP_V); e = __expf(f);
        atomicAdd(&snum[c][s0], e * f); atomicAdd(&sden[c][s0], e);
        f = fminf(fmaxf(fv.y + ev.y, -CLAMP_V), CLAMP_V); e = __expf(f);
        atomicAdd(&snum[c][s1], e * f); atomicAdd(&sden[c][s1], e);
        f = fminf(fmaxf(fv.z + ev.z, -CLAMP_V), CLAMP_V); e = __expf(f);
        atomicAdd(&snum[c][s2], e * f); atomicAdd(&sden[c][s2], e);
        f = fminf(fmaxf(fv.w + ev.w, -CLAMP_V), CLAMP_V); e = __expf(f);
        atomicAdd(&snum[c][s3], e * f); atomicAdd(&sden[c][s3], e);
    }
    __syncthreads();

    // write partials [C][S] (drop segment slot 0)
    float* out_num = part_num + (size_t)(b * BLKS_PER_B + blk) * (NCH * NS);
    float* out_den = part_den + (size_t)(b * BLKS_PER_B + blk) * (NCH * NS);
    for (int i = tid; i < NCH * NS; i += 256) {
        const int c  = i >> 6;
        const int ss = (i & 63) + 1;
        out_num[i] = snum[c][ss];
        out_den[i] = sden[c][ss];
    }
}

// ---------------- Kernel 2: merge partials -> seg_feat [B][S][C] -------------
// grid: B*C*S / 256 = 128 blocks
__global__ __launch_bounds__(256) void merge_seg(
    const float* __restrict__ part_num,
    const float* __restrict__ part_den,
    float* __restrict__ seg_feat)      // [B, S, C]
{
    const int g = blockIdx.x * 256 + threadIdx.x;   // over B*C*S = 32768
    const int b = g >> 12;
    const int c = (g >> 6) & 63;
    const int s = g & 63;

    float num = 0.f, den = 0.f;
    const size_t base = (size_t)b * BLKS_PER_B * (NCH * NS) + c * NS + s;
    #pragma unroll 8
    for (int blk = 0; blk < BLKS_PER_B; ++blk) {
        num += part_num[base + (size_t)blk * (NCH * NS)];
        den += part_den[base + (size_t)blk * (NCH * NS)];
    }
    seg_feat[(size_t)b * (NS * NCH) + s * NCH + c] = num / (den + EPS_V);
}

// ---------------- Kernel 3: heads (node GEMM, action dot, constants) ---------
// grid: B*S = 512 blocks, 256 threads; block bs handles (b = bs>>6, s = bs&63)
__global__ __launch_bounds__(256) void heads(
    const float* __restrict__ seg_feat,  // [B,S,C]
    const float* __restrict__ Wn,        // [C,NC]
    const float* __restrict__ bn,        // [NC]
    const float* __restrict__ Wa,        // [C]
    const float* __restrict__ ba,        // [1]
    float* __restrict__ out)             // concat: node|action|values|weights
{
    __shared__ float row[NCH];
    const int bs  = blockIdx.x;
    const int tid = threadIdx.x;

    if (tid < NCH) row[tid] = seg_feat[(size_t)bs * NCH + tid];
    __syncthreads();

    // node logits: thread tid -> class tid
    float acc = bn[tid];
    #pragma unroll
    for (int c = 0; c < NCH; ++c) acc += row[c] * Wn[c * NNC + tid];
    out[(size_t)bs * NNC + tid] = acc;

    // action logit: first wave (lanes 0..63) reduces row * Wa
    if (tid < 64) {
        float v = row[tid] * Wa[tid];
        #pragma unroll
        for (int m = 32; m >= 1; m >>= 1) v += __shfl_xor(v, m, 64);
        if (tid == 0) out[NB * NS * NNC + bs] = v + ba[0];
    }

    // segment_values / segment_weights (as f32 into concat f32 buffer)
    if (tid == 64) {
        out[NB * NS * NNC + NB * NS + bs]     = (float)((bs & 63) + 1);
        out[NB * NS * NNC + 2 * NB * NS + bs] = 1.0f;
    }
}

extern "C" void kernel_launch(void* const* d_in, const int* in_sizes, int n_in,
                              void* d_out, int out_size, void* d_ws, size_t ws_size,
                              hipStream_t stream) {
    const float* feat = (const float*)d_in[0];   // [8,64,256,256]
    const float* emb  = (const float*)d_in[1];   // [64,256,256]
    const float* Wn   = (const float*)d_in[2];   // [64,256]
    const float* bn   = (const float*)d_in[3];   // [256]
    const float* Wa   = (const float*)d_in[4];   // [64]
    const float* ba   = (const float*)d_in[5];   // [1]
    const int*   seg  = (const int*)d_in[6];     // [8,256,256]
    float* out = (float*)d_out;

    // workspace layout (floats):
    //   part_num : [8][64][64][64]  = 2,097,152
    //   part_den : [8][64][64][64]  = 2,097,152
    //   seg_feat : [8][64][64]      =    32,768
    float* part_num = (float*)d_ws;
    float* part_den = part_num + (size_t)NB * BLKS_PER_B * NCH * NS;
    float* seg_feat = part_den + (size_t)NB * BLKS_PER_B * NCH * NS;

    pool_partial<<<dim3(BLKS_PER_B, NB), 256, 0, stream>>>(feat, emb, seg, part_num, part_den);
    merge_seg<<<dim3((NB * NCH * NS) / 256), 256, 0, stream>>>(part_num, part_den, seg_feat);
    heads<<<dim3(NB * NS), 256, 0, stream>>>(seg_feat, Wn, bn, Wa, ba, out);
}

// Round 11
// 288.330 us; speedup vs baseline: 1.7490x; 1.7490x over previous
//
#include <hip/hip_runtime.h>
#include <math.h>

// Problem constants
#define NB 8
#define NCH 64
#define NP 65536            // 256*256 pixels
#define NS 64               // segments 1..64
#define NNC 256             // node classes
#define CLAMP_V 10.0f
#define EPS_V 1e-5f

#define BLKS_PER_B 64
#define PB 1024             // pixels per block
#define TP 64               // tile pixels
#define NT (PB / TP)        // 16 tiles per block

// ---------------- Kernel 1: two-phase pooling, no atomics --------------------
// grid (BLKS_PER_B, NB), block 256 (4 waves).
// Phase A: coalesced float4 loads of a [64ch][64px] tile; store f=feat+emb to
//          LDS tile[c][p] (stride 65 -> 2-way banks, free).
// Phase B: lane=channel. Segment id per pixel is wave-uniform; wave w owns
//          segments [16w+1,16w+16] (wave-uniform branch), so plain LDS RMW on
//          acc[lane][s] is race-free: no atomics, no same-address collisions.
__global__ __launch_bounds__(256) void pool2(
    const float* __restrict__ feat,   // [B,C,H*W]
    const float* __restrict__ emb,    // [C,H*W]
    const int*   __restrict__ seg,    // [B,H*W]
    float* __restrict__ part_num,     // [B, BLKS_PER_B, C, S]
    float* __restrict__ part_den)     // [B, BLKS_PER_B, C, S]
{
    __shared__ float tile[NCH][TP + 1];   // unclamped f      16.6 KB
    __shared__ float anum[NCH][NS + 1];   // [c][s], s=1..64  16.6 KB
    __shared__ float aden[NCH][NS + 1];   //                  16.6 KB
    __shared__ int   segc[PB];            //                   4.0 KB  (54 KB tot)

    const int tid  = threadIdx.x;
    const int blk  = blockIdx.x;
    const int b    = blockIdx.y;
    const int wave = tid >> 6;
    const int lane = tid & 63;

    // zero accumulators
    for (int i = tid; i < NCH * (NS + 1); i += 256) {
        (&anum[0][0])[i] = 0.f;
        (&aden[0][0])[i] = 0.f;
    }
    // cache this block's 1024 segment ids (int4-coalesced)
    reinterpret_cast<int4*>(segc)[tid] =
        reinterpret_cast<const int4*>(seg + (size_t)b * NP + (size_t)blk * PB)[tid];
    __syncthreads();

    // phase-A mapping: lane -> (channel-in-group, float4-slot)
    const int cg = lane >> 4;     // 0..3
    const int pf = lane & 15;     // 0..15 (float4 index within 64-px tile)
    const float4* f4 = reinterpret_cast<const float4*>(feat)
                     + (size_t)b * NCH * (NP / 4) + (size_t)blk * (PB / 4) + pf;
    const float4* e4 = reinterpret_cast<const float4*>(emb)
                     + (size_t)blk * (PB / 4) + pf;

    for (int t = 0; t < NT; ++t) {
        const int p0 = t * TP;

        // ---- phase A: stage f = feat + emb into tile (coalesced) ----
        #pragma unroll
        for (int k = 0; k < 4; ++k) {
            const int c = wave * 16 + k * 4 + cg;
            const float4 fv = f4[(size_t)c * (NP / 4) + (p0 >> 2)];
            const float4 ev = e4[(size_t)c * (NP / 4) + (p0 >> 2)];
            tile[c][pf * 4 + 0] = fv.x + ev.x;
            tile[c][pf * 4 + 1] = fv.y + ev.y;
            tile[c][pf * 4 + 2] = fv.z + ev.z;
            tile[c][pf * 4 + 3] = fv.w + ev.w;
        }
        __syncthreads();

        // ---- phase B: lane=channel, wave owns its segment range ----
        for (int j = 0; j < TP; ++j) {
            const int s = segc[p0 + j];                 // wave-uniform broadcast
            if (((s - 1) >> 4) == wave) {               // wave-uniform branch
                const float f  = tile[lane][j];         // conflict-free
                const float fc = fminf(fmaxf(f, -CLAMP_V), CLAMP_V);
                const float e  = __expf(fc);
                anum[lane][s] += e * f;                 // unclamped f (matches ref)
                aden[lane][s] += e;
            }
        }
        __syncthreads();
    }

    // write partials [C][S] (drop s=0 slot), coalesced
    float* on = part_num + (size_t)(b * BLKS_PER_B + blk) * (NCH * NS);
    float* od = part_den + (size_t)(b * BLKS_PER_B + blk) * (NCH * NS);
    for (int i = tid; i < NCH * NS; i += 256) {
        const int c  = i >> 6;
        const int ss = (i & 63) + 1;
        on[i] = anum[c][ss];
        od[i] = aden[c][ss];
    }
}

// ---------------- Kernel 2: fused merge + heads ------------------------------
// grid: B*S = 512 blocks, 256 threads; block bs = (b = bs>>6, s = bs&63).
// Step 1: reduce 64 per-block partials for this (b,s) row -> seg_feat[64].
// Step 2: node logits (thread=class), action dot, constants.
__global__ __launch_bounds__(256) void tail(
    const float* __restrict__ part_num,
    const float* __restrict__ part_den,
    const float* __restrict__ Wn,        // [C,NC]
    const float* __restrict__ bn,        // [NC]
    const float* __restrict__ Wa,        // [C]
    const float* __restrict__ ba,        // [1]
    float* __restrict__ out)             // concat: node|action|values|weights
{
    __shared__ float rnum[4][NCH];
    __shared__ float rden[4][NCH];
    __shared__ float row[NCH];

    const int bs  = blockIdx.x;
    const int b   = bs >> 6;
    const int s   = bs & 63;
    const int tid = threadIdx.x;
    const int c   = tid & 63;
    const int q   = tid >> 6;            // quarter: 16 partial-blocks each

    float num = 0.f, den = 0.f;
    const size_t base = (((size_t)b * 64 + q * 16) * 64 + c) * 64 + s;
    #pragma unroll
    for (int k = 0; k < 16; ++k) {
        num += part_num[base + (size_t)k * 4096];   // blk stride = 64*64
        den += part_den[base + (size_t)k * 4096];
    }
    rnum[q][c] = num;
    rden[q][c] = den;
    __syncthreads();

    if (tid < NCH) {
        const float n2 = rnum[0][tid] + rnum[1][tid] + rnum[2][tid] + rnum[3][tid];
        const float d2 = rden[0][tid] + rden[1][tid] + rden[2][tid] + rden[3][tid];
        row[tid] = n2 / (d2 + EPS_V);
    }
    __syncthreads();

    // node logits: thread tid -> class tid
    float acc = bn[tid];
    #pragma unroll
    for (int cc = 0; cc < NCH; ++cc) acc += row[cc] * Wn[cc * NNC + tid];
    out[(size_t)bs * NNC + tid] = acc;

    // action logit: first wave reduces row * Wa
    if (tid < 64) {
        float v = row[tid] * Wa[tid];
        #pragma unroll
        for (int m = 32; m >= 1; m >>= 1) v += __shfl_xor(v, m, 64);
        if (tid == 0) out[NB * NS * NNC + bs] = v + ba[0];
    }

    // segment_values / segment_weights (as f32 into concat f32 buffer)
    if (tid == 64) {
        out[NB * NS * NNC + NB * NS + bs]     = (float)(s + 1);
        out[NB * NS * NNC + 2 * NB * NS + bs] = 1.0f;
    }
}

extern "C" void kernel_launch(void* const* d_in, const int* in_sizes, int n_in,
                              void* d_out, int out_size, void* d_ws, size_t ws_size,
                              hipStream_t stream) {
    const float* feat = (const float*)d_in[0];   // [8,64,256,256]
    const float* emb  = (const float*)d_in[1];   // [64,256,256]
    const float* Wn   = (const float*)d_in[2];   // [64,256]
    const float* bn   = (const float*)d_in[3];   // [256]
    const float* Wa   = (const float*)d_in[4];   // [64]
    const float* ba   = (const float*)d_in[5];   // [1]
    const int*   seg  = (const int*)d_in[6];     // [8,256,256]
    float* out = (float*)d_out;

    // workspace (floats): part_num [8][64][64][64] = 2,097,152
    //                     part_den [8][64][64][64] = 2,097,152   (16.8 MB)
    float* part_num = (float*)d_ws;
    float* part_den = part_num + (size_t)NB * BLKS_PER_B * NCH * NS;

    pool2<<<dim3(BLKS_PER_B, NB), 256, 0, stream>>>(feat, emb, seg, part_num, part_den);
    tail<<<dim3(NB * NS), 256, 0, stream>>>(part_num, part_den, Wn, bn, Wa, ba, out);
}